// Round 5
// baseline (26.641 us; speedup 1.0000x reference)
//
#include <hip/hip_runtime.h>

// CrossNet: x_{l+1} = x0 * (xl . w_l) + xl + b_l, 3 layers, fused, one pass.
// R4: software-pipelined 2-pairs-per-wave. Each wave owns 4 rows; the x-loads
// for pair 1 are issued BEFORE pair 0's compute (3 serial shfl-butterfly
// chains, ~1000 cy) so HBM stays busy during the reduce phases and pair 1's
// load wait is pre-satisfied. Keeps R3's 2-row ILP (interleaved butterflies,
// shared k/b loads). ~128 VGPR -> 4 waves/SIMD.

#define CN_BATCH 16384
#define CN_DIM   1024
#define CN_LAYERS 3
#define CN_ITERS 2          // row-pairs per wave (pipeline depth 2)

typedef float f32x4 __attribute__((ext_vector_type(4)));

__global__ __launch_bounds__(256) void crossnet_kernel(
    const float* __restrict__ x,
    const float* __restrict__ kernels,
    const float* __restrict__ bias,
    float* __restrict__ out)
{
    const int wave = threadIdx.x >> 6;             // 0..3
    const int lane = threadIdx.x & 63;
    const int gw   = (blockIdx.x << 2) + wave;     // global wave id
    const int row0 = gw * (2 * CN_ITERS);          // 4 consecutive rows per wave
    const int eoff = lane * 4;                     // element offset within 256-chunk

    // Current pair (rows row0, row0+1) — load immediately.
    f32x4 x0A[4], x0B[4], xlA[4], xlB[4];
    {
        const float* pA = x + (size_t)row0 * CN_DIM;
        const float* pB = pA + CN_DIM;
#pragma unroll
        for (int j = 0; j < 4; ++j) {
            x0A[j] = *reinterpret_cast<const f32x4*>(pA + j * 256 + eoff);
            x0B[j] = *reinterpret_cast<const f32x4*>(pB + j * 256 + eoff);
        }
    }

#pragma unroll
    for (int it = 0; it < CN_ITERS; ++it) {
        // Prefetch next pair: issued before this pair's compute chain.
        f32x4 nA[4], nB[4];
        if (it + 1 < CN_ITERS) {
            const float* qA = x + (size_t)(row0 + 2 * (it + 1)) * CN_DIM;
            const float* qB = qA + CN_DIM;
#pragma unroll
            for (int j = 0; j < 4; ++j) {
                nA[j] = *reinterpret_cast<const f32x4*>(qA + j * 256 + eoff);
                nB[j] = *reinterpret_cast<const f32x4*>(qB + j * 256 + eoff);
            }
        }

#pragma unroll
        for (int j = 0; j < 4; ++j) { xlA[j] = x0A[j]; xlB[j] = x0B[j]; }

#pragma unroll
        for (int i = 0; i < CN_LAYERS; ++i) {
            const float* krow = kernels + i * CN_DIM;
            const float* brow = bias    + i * CN_DIM;

            float pA = 0.0f, pB = 0.0f;
#pragma unroll
            for (int j = 0; j < 4; ++j) {
                f32x4 k = *reinterpret_cast<const f32x4*>(krow + j * 256 + eoff);
                pA = fmaf(xlA[j].x, k.x, pA);  pB = fmaf(xlB[j].x, k.x, pB);
                pA = fmaf(xlA[j].y, k.y, pA);  pB = fmaf(xlB[j].y, k.y, pB);
                pA = fmaf(xlA[j].z, k.z, pA);  pB = fmaf(xlB[j].z, k.z, pB);
                pA = fmaf(xlA[j].w, k.w, pA);  pB = fmaf(xlB[j].w, k.w, pB);
            }
            // Two interleaved 64-lane butterflies (independent chains).
#pragma unroll
            for (int o = 32; o >= 1; o >>= 1) {
                pA += __shfl_xor(pA, o, 64);
                pB += __shfl_xor(pB, o, 64);
            }
            const float sA = pA, sB = pB;

#pragma unroll
            for (int j = 0; j < 4; ++j) {
                f32x4 b = *reinterpret_cast<const f32x4*>(brow + j * 256 + eoff);
                xlA[j].x = fmaf(x0A[j].x, sA, xlA[j].x) + b.x;
                xlA[j].y = fmaf(x0A[j].y, sA, xlA[j].y) + b.y;
                xlA[j].z = fmaf(x0A[j].z, sA, xlA[j].z) + b.z;
                xlA[j].w = fmaf(x0A[j].w, sA, xlA[j].w) + b.w;
                xlB[j].x = fmaf(x0B[j].x, sB, xlB[j].x) + b.x;
                xlB[j].y = fmaf(x0B[j].y, sB, xlB[j].y) + b.y;
                xlB[j].z = fmaf(x0B[j].z, sB, xlB[j].z) + b.z;
                xlB[j].w = fmaf(x0B[j].w, sB, xlB[j].w) + b.w;
            }
        }

        float* oA = out + (size_t)(row0 + 2 * it) * CN_DIM;
        float* oB = oA + CN_DIM;
#pragma unroll
        for (int j = 0; j < 4; ++j) {
            *reinterpret_cast<f32x4*>(oA + j * 256 + eoff) = xlA[j];
            *reinterpret_cast<f32x4*>(oB + j * 256 + eoff) = xlB[j];
        }

        // Rotate pipeline.
        if (it + 1 < CN_ITERS) {
#pragma unroll
            for (int j = 0; j < 4; ++j) { x0A[j] = nA[j]; x0B[j] = nB[j]; }
        }
    }
}

extern "C" void kernel_launch(void* const* d_in, const int* in_sizes, int n_in,
                              void* d_out, int out_size, void* d_ws, size_t ws_size,
                              hipStream_t stream) {
    const float* x       = (const float*)d_in[0];
    const float* kernels = (const float*)d_in[1];
    const float* bias    = (const float*)d_in[2];
    float* out           = (float*)d_out;

    // 4 waves/block, 4 rows/wave -> 16 rows/block.
    dim3 grid(CN_BATCH / (4 * 2 * CN_ITERS));
    dim3 block(256);
    crossnet_kernel<<<grid, block, 0, stream>>>(x, kernels, bias, out);
}

// Round 6
// 25.239 us; speedup vs baseline: 1.0556x; 1.0556x over previous
//
#include <hip/hip_runtime.h>

// CrossNet: x_{l+1} = x0 * (xl . w_l) + xl + b_l, 3 layers, fused, one pass.
// R5: R3 structure (best: 25.99us — 2 rows/wave ILP, interleaved butterflies,
// shared k/b loads, ~90 VGPR / 5 waves/SIMD) + NONTEMPORAL STORES ONLY.
// R2 post-mortem: NT loads hurt (x is L3-resident across graph replays);
// NT stores are the untested orthogonal half — out is write-once, never
// re-read during timing, so bypassing L2/L3 write-allocate keeps the cache
// clean for x. R4 post-mortem: deeper per-wave pipelining (160 VGPR) loses
// to occupancy — don't go past 2 rows/wave.

#define CN_BATCH 16384
#define CN_DIM   1024
#define CN_LAYERS 3

typedef float f32x4 __attribute__((ext_vector_type(4)));

__global__ __launch_bounds__(256) void crossnet_kernel(
    const float* __restrict__ x,
    const float* __restrict__ kernels,
    const float* __restrict__ bias,
    float* __restrict__ out)
{
    const int wave = threadIdx.x >> 6;                 // 0..3
    const int lane = threadIdx.x & 63;
    const int pair = (blockIdx.x << 2) + wave;         // wave-pair index
    const int rowA = pair * 2;                         // two adjacent rows per wave
    const int rowB = rowA + 1;

    const float* xrowA = x + (size_t)rowA * CN_DIM;
    const float* xrowB = x + (size_t)rowB * CN_DIM;

    // Lane l covers elements {j*256 + l*4 .. +3}, j=0..3 (coalesced 16B/lane).
    f32x4 x0A[4], xlA[4], x0B[4], xlB[4];
#pragma unroll
    for (int j = 0; j < 4; ++j) {
        x0A[j] = *reinterpret_cast<const f32x4*>(xrowA + j * 256 + lane * 4);
        x0B[j] = *reinterpret_cast<const f32x4*>(xrowB + j * 256 + lane * 4);
    }
#pragma unroll
    for (int j = 0; j < 4; ++j) { xlA[j] = x0A[j]; xlB[j] = x0B[j]; }

#pragma unroll
    for (int i = 0; i < CN_LAYERS; ++i) {
        const float* krow = kernels + i * CN_DIM;
        const float* brow = bias    + i * CN_DIM;

        // Partial dots for both rows over this lane's 16 elements; k shared.
        float pA = 0.0f, pB = 0.0f;
#pragma unroll
        for (int j = 0; j < 4; ++j) {
            f32x4 k = *reinterpret_cast<const f32x4*>(krow + j * 256 + lane * 4);
            pA = fmaf(xlA[j].x, k.x, pA);  pB = fmaf(xlB[j].x, k.x, pB);
            pA = fmaf(xlA[j].y, k.y, pA);  pB = fmaf(xlB[j].y, k.y, pB);
            pA = fmaf(xlA[j].z, k.z, pA);  pB = fmaf(xlB[j].z, k.z, pB);
            pA = fmaf(xlA[j].w, k.w, pA);  pB = fmaf(xlB[j].w, k.w, pB);
        }
        // Two interleaved 64-lane butterflies (independent latency chains).
#pragma unroll
        for (int off = 32; off >= 1; off >>= 1) {
            pA += __shfl_xor(pA, off, 64);
            pB += __shfl_xor(pB, off, 64);
        }
        const float sA = pA, sB = pB;

        // xl = x0 * s + xl + bias_i  (b shared by both rows)
#pragma unroll
        for (int j = 0; j < 4; ++j) {
            f32x4 b = *reinterpret_cast<const f32x4*>(brow + j * 256 + lane * 4);
            xlA[j].x = fmaf(x0A[j].x, sA, xlA[j].x) + b.x;
            xlA[j].y = fmaf(x0A[j].y, sA, xlA[j].y) + b.y;
            xlA[j].z = fmaf(x0A[j].z, sA, xlA[j].z) + b.z;
            xlA[j].w = fmaf(x0A[j].w, sA, xlA[j].w) + b.w;
            xlB[j].x = fmaf(x0B[j].x, sB, xlB[j].x) + b.x;
            xlB[j].y = fmaf(x0B[j].y, sB, xlB[j].y) + b.y;
            xlB[j].z = fmaf(x0B[j].z, sB, xlB[j].z) + b.z;
            xlB[j].w = fmaf(x0B[j].w, sB, xlB[j].w) + b.w;
        }
    }

    float* orowA = out + (size_t)rowA * CN_DIM;
    float* orowB = out + (size_t)rowB * CN_DIM;
#pragma unroll
    for (int j = 0; j < 4; ++j) {
        __builtin_nontemporal_store(xlA[j],
            reinterpret_cast<f32x4*>(orowA + j * 256 + lane * 4));
        __builtin_nontemporal_store(xlB[j],
            reinterpret_cast<f32x4*>(orowB + j * 256 + lane * 4));
    }
}

extern "C" void kernel_launch(void* const* d_in, const int* in_sizes, int n_in,
                              void* d_out, int out_size, void* d_ws, size_t ws_size,
                              hipStream_t stream) {
    const float* x       = (const float*)d_in[0];
    const float* kernels = (const float*)d_in[1];
    const float* bias    = (const float*)d_in[2];
    float* out           = (float*)d_out;

    // 2 rows per wave, 4 waves per block -> 8 rows per block.
    dim3 grid(CN_BATCH / 8);
    dim3 block(256);
    crossnet_kernel<<<grid, block, 0, stream>>>(x, kernels, bias, out);
}

// Round 7
// 24.900 us; speedup vs baseline: 1.0699x; 1.0136x over previous
//
#include <hip/hip_runtime.h>

// CrossNet flattened: x_{l+1} = x0*s_l + x_l + b_l is affine in x0, so
//   out = x * (1 + s1 + s2 + s3) + (b1+b2+b3)
//   a_i = x . k_i   (3 INDEPENDENT dots on original x)
//   c2 = b1 . k2,  c3 = (b1+b2) . k3   (row-independent scalars)
//   s1 = a1;  s2 = (1+s1)*a2 + c2;  s3 = (1+s1+s2)*a3 + c3
// R6: collapses 3 sequential {dot+butterfly+update} chains into ONE dot pass,
// ONE batch of 8 interleaved butterflies (6-deep), ONE update pass.
// Keeps R3's 2-rows/wave ILP + R5's NT stores (out is write-once; keep L3
// clean for the replay-resident x). c2/c3/B recomputed per wave (VALU is
// idle; avoids a second launch).

#define CN_BATCH 16384
#define CN_DIM   1024

typedef float f32x4 __attribute__((ext_vector_type(4)));

__global__ __launch_bounds__(256) void crossnet_kernel(
    const float* __restrict__ x,
    const float* __restrict__ kernels,
    const float* __restrict__ bias,
    float* __restrict__ out)
{
    const int wave = threadIdx.x >> 6;              // 0..3
    const int lane = threadIdx.x & 63;
    const int pair = (blockIdx.x << 2) + wave;
    const int rowA = pair * 2;                      // two adjacent rows per wave
    const int eoff = lane * 4;

    const float* xrowA = x + (size_t)rowA * CN_DIM;
    const float* xrowB = xrowA + CN_DIM;

    const float* k1 = kernels;
    const float* k2 = kernels + CN_DIM;
    const float* k3 = kernels + 2 * CN_DIM;
    const float* b1 = bias;
    const float* b2 = bias + CN_DIM;
    const float* b3 = bias + 2 * CN_DIM;

    // Load both x rows (coalesced 16B/lane; lane l covers {j*256+4l..+3}).
    f32x4 x0A[4], x0B[4];
#pragma unroll
    for (int j = 0; j < 4; ++j) {
        x0A[j] = *reinterpret_cast<const f32x4*>(xrowA + j * 256 + eoff);
        x0B[j] = *reinterpret_cast<const f32x4*>(xrowB + j * 256 + eoff);
    }

    // One pass: 6 row-dots (a1..a3 x 2 rows) + 2 shared dots (c2,c3) + Bsum.
    float a1A = 0.f, a2A = 0.f, a3A = 0.f;
    float a1B = 0.f, a2B = 0.f, a3B = 0.f;
    float c2  = 0.f, c3  = 0.f;
    f32x4 Bs[4];
#pragma unroll
    for (int j = 0; j < 4; ++j) {
        f32x4 vk1 = *reinterpret_cast<const f32x4*>(k1 + j * 256 + eoff);
        f32x4 vk2 = *reinterpret_cast<const f32x4*>(k2 + j * 256 + eoff);
        f32x4 vk3 = *reinterpret_cast<const f32x4*>(k3 + j * 256 + eoff);
        f32x4 vb1 = *reinterpret_cast<const f32x4*>(b1 + j * 256 + eoff);
        f32x4 vb2 = *reinterpret_cast<const f32x4*>(b2 + j * 256 + eoff);
        f32x4 vb3 = *reinterpret_cast<const f32x4*>(b3 + j * 256 + eoff);
        f32x4 b12 = vb1 + vb2;
        Bs[j] = b12 + vb3;
#pragma unroll
        for (int c = 0; c < 4; ++c) {
            a1A = fmaf(x0A[j][c], vk1[c], a1A);
            a2A = fmaf(x0A[j][c], vk2[c], a2A);
            a3A = fmaf(x0A[j][c], vk3[c], a3A);
            a1B = fmaf(x0B[j][c], vk1[c], a1B);
            a2B = fmaf(x0B[j][c], vk2[c], a2B);
            a3B = fmaf(x0B[j][c], vk3[c], a3B);
            c2  = fmaf(vb1[c],    vk2[c], c2);
            c3  = fmaf(b12[c],    vk3[c], c3);
        }
    }

    // 8 fully-interleaved 64-lane butterflies (6-deep serial, not 18).
#pragma unroll
    for (int o = 32; o >= 1; o >>= 1) {
        a1A += __shfl_xor(a1A, o, 64);
        a2A += __shfl_xor(a2A, o, 64);
        a3A += __shfl_xor(a3A, o, 64);
        a1B += __shfl_xor(a1B, o, 64);
        a2B += __shfl_xor(a2B, o, 64);
        a3B += __shfl_xor(a3B, o, 64);
        c2  += __shfl_xor(c2,  o, 64);
        c3  += __shfl_xor(c3,  o, 64);
    }

    // Scalar recurrence (per row): t_l = 1 + s1 + ... + s_l.
    const float t1A = 1.0f + a1A;
    const float s2A = fmaf(t1A, a2A, c2);
    const float t2A = t1A + s2A;
    const float s3A = fmaf(t2A, a3A, c3);
    const float t3A = t2A + s3A;

    const float t1B = 1.0f + a1B;
    const float s2B = fmaf(t1B, a2B, c2);
    const float t2B = t1B + s2B;
    const float s3B = fmaf(t2B, a3B, c3);
    const float t3B = t2B + s3B;

    // Single update pass: out = x * t3 + (b1+b2+b3). NT stores (write-once).
    float* orowA = out + (size_t)rowA * CN_DIM;
    float* orowB = orowA + CN_DIM;
#pragma unroll
    for (int j = 0; j < 4; ++j) {
        f32x4 oA, oB;
#pragma unroll
        for (int c = 0; c < 4; ++c) {
            oA[c] = fmaf(x0A[j][c], t3A, Bs[j][c]);
            oB[c] = fmaf(x0B[j][c], t3B, Bs[j][c]);
        }
        __builtin_nontemporal_store(oA,
            reinterpret_cast<f32x4*>(orowA + j * 256 + eoff));
        __builtin_nontemporal_store(oB,
            reinterpret_cast<f32x4*>(orowB + j * 256 + eoff));
    }
}

extern "C" void kernel_launch(void* const* d_in, const int* in_sizes, int n_in,
                              void* d_out, int out_size, void* d_ws, size_t ws_size,
                              hipStream_t stream) {
    const float* x       = (const float*)d_in[0];
    const float* kernels = (const float*)d_in[1];
    const float* bias    = (const float*)d_in[2];
    float* out           = (float*)d_out;

    // 2 rows/wave, 4 waves/block -> 8 rows/block.
    dim3 grid(CN_BATCH / 8);
    dim3 block(256);
    crossnet_kernel<<<grid, block, 0, stream>>>(x, kernels, bias, out);
}